// Round 1
// baseline (10381.056 us; speedup 1.0000x reference)
//
#include <hip/hip_runtime.h>

#define TT 2048
#define NH 15

#if __has_builtin(__builtin_amdgcn_exp2f)
#define EXP2(x) __builtin_amdgcn_exp2f(x)
#else
#define EXP2(x) exp2f(x)
#endif
#if __has_builtin(__builtin_amdgcn_rcpf)
#define RCP(x) __builtin_amdgcn_rcpf(x)
#else
#define RCP(x) (1.0f / (x))
#endif

__device__ __forceinline__ float sigm(float x) {
    // 1/(1+exp(-x)) ; exp(-x) = 2^(-x*log2(e))
    float e = EXP2(x * -1.4426950408889634f);
    return RCP(1.0f + e);
}

__device__ __forceinline__ float tanh_fast(float x) {
    // tanh(x) = 1 - 2/(e^(2x)+1) ; e^(2x) = 2^(2*log2(e)*x)
    float e = EXP2(x * 2.8853900817779268f);
    return fmaf(-2.0f, RCP(e + 1.0f), 1.0f);
}

__device__ __forceinline__ float shfl16(float v, int src) {
    return __shfl(v, src, 16);
}

__device__ __forceinline__ void ew(const float z[4], float& h, float& c) {
    float i_ = sigm(z[0]);
    float f_ = sigm(z[1]);
    float g_ = tanh_fast(z[2]);
    float o_ = sigm(z[3]);
    c = fmaf(f_, c, i_ * g_);
    h = o_ * tanh_fast(c);
}

// Layer 1: scalar input x, hidden h (distributed one unit per lane across 16 lanes)
__device__ __forceinline__ void cell1(const float wi[4], const float wh[4][NH], const float bb[4],
                                      float x, float& h, float& c) {
    float z[4];
#pragma unroll
    for (int g = 0; g < 4; ++g) z[g] = fmaf(wi[g], x, bb[g]);
#pragma unroll
    for (int cc = 0; cc < NH; ++cc) {
        float hb = shfl16(h, cc);
#pragma unroll
        for (int g = 0; g < 4; ++g) z[g] = fmaf(wh[g][cc], hb, z[g]);
    }
    ew(z, h, c);
}

// Layers 2/3: input vector = previous layer's h (distributed), own h (distributed)
__device__ __forceinline__ void cell2(const float wi[4][NH], const float wh[4][NH], const float bb[4],
                                      float hin, float& h, float& c) {
    float z[4];
#pragma unroll
    for (int g = 0; g < 4; ++g) z[g] = bb[g];
#pragma unroll
    for (int cc = 0; cc < NH; ++cc) {
        float a = shfl16(hin, cc);
        float b = shfl16(h, cc);
#pragma unroll
        for (int g = 0; g < 4; ++g) z[g] = fmaf(wi[g][cc], a, fmaf(wh[g][cc], b, z[g]));
    }
    ew(z, h, c);
}

__global__ __launch_bounds__(256, 1)
void lstm3_kernel(const float* __restrict__ input,
                  const float* __restrict__ w_ih1, const float* __restrict__ w_hh1,
                  const float* __restrict__ b_ih1, const float* __restrict__ b_hh1,
                  const float* __restrict__ w_ih2, const float* __restrict__ w_hh2,
                  const float* __restrict__ b_ih2, const float* __restrict__ b_hh2,
                  const float* __restrict__ w_ih3, const float* __restrict__ w_hh3,
                  const float* __restrict__ b_ih3, const float* __restrict__ b_hh3,
                  const float* __restrict__ w_lin, const float* __restrict__ b_lin,
                  float* __restrict__ out, int B)
{
    const int tid = threadIdx.x;
    const int k = tid & 15;                              // hidden-unit index (0..15, 15 = pad)
    const int grp = (blockIdx.x * blockDim.x + tid) >> 4; // element group, 0..B/2-1
    const int e0 = grp;
    const int e1 = grp + (B >> 1);
    const bool act = (k < NH);

    // ---- load lane-private weights into registers (zero for the pad lane) ----
    float wi1[4], b1[4], wh1[4][NH];
    float wi2[4][NH], wh2[4][NH], b2[4];
    float wi3[4][NH], wh3[4][NH], b3[4];
#pragma unroll
    for (int g = 0; g < 4; ++g) {
        const int r = g * NH + (act ? k : 0);
        wi1[g] = act ? w_ih1[r] : 0.f;
        b1[g] = act ? (b_ih1[r] + b_hh1[r]) : 0.f;
        b2[g] = act ? (b_ih2[r] + b_hh2[r]) : 0.f;
        b3[g] = act ? (b_ih3[r] + b_hh3[r]) : 0.f;
#pragma unroll
        for (int c = 0; c < NH; ++c) {
            wh1[g][c] = act ? w_hh1[r * NH + c] : 0.f;
            wi2[g][c] = act ? w_ih2[r * NH + c] : 0.f;
            wh2[g][c] = act ? w_hh2[r * NH + c] : 0.f;
            wi3[g][c] = act ? w_ih3[r * NH + c] : 0.f;
            wh3[g][c] = act ? w_hh3[r * NH + c] : 0.f;
        }
    }
    const float wl = act ? w_lin[k] : 0.f;
    const float bl = b_lin[0];

    // ---- state ----
    float h1a = 0.f, c1a = 0.f, h2a = 0.f, c2a = 0.f, h3a = 0.f, c3a = 0.f;
    float h1b = 0.f, c1b = 0.f, h2b = 0.f, c2b = 0.f, h3b = 0.f, c3b = 0.f;

    const float* xpa = input + (size_t)e0 * TT;
    const float* xpb = input + (size_t)e1 * TT;
    float* opa = out + (size_t)e0 * TT;
    float* opb = out + (size_t)e1 * TT;

    for (int t0 = 0; t0 < TT; t0 += 16) {
        // coalesced 16-step input tile (lane k holds x[t0+k])
        float xba = xpa[t0 + k];
        float xbb = xpb[t0 + k];
        float ya = 0.f, yb = 0.f;
#pragma unroll 1
        for (int tt = 0; tt < 16; ++tt) {
            float xa = shfl16(xba, tt);
            float xb = shfl16(xbb, tt);

            cell1(wi1, wh1, b1, xa, h1a, c1a);
            cell1(wi1, wh1, b1, xb, h1b, c1b);
            cell2(wi2, wh2, b2, h1a, h2a, c2a);
            cell2(wi2, wh2, b2, h1b, h2b, c2b);
            cell2(wi3, wh3, b3, h2a, h3a, c3a);
            cell2(wi3, wh3, b3, h2b, h3b, c3b);

            // out = h3 . w_lin + b_lin ; butterfly sum over the 16-lane group
            float pa = wl * h3a;
            float pb = wl * h3b;
#pragma unroll
            for (int m = 1; m < 16; m <<= 1) {
                pa += __shfl_xor(pa, m, 16);
                pb += __shfl_xor(pb, m, 16);
            }
            pa += bl;
            pb += bl;
            ya = (tt == k) ? pa : ya;   // lane k keeps step t0+k's output
            yb = (tt == k) ? pb : yb;
        }
        // coalesced 16-step output tile
        opa[t0 + k] = ya;
        opb[t0 + k] = yb;
    }
}

extern "C" void kernel_launch(void* const* d_in, const int* in_sizes, int n_in,
                              void* d_out, int out_size, void* d_ws, size_t ws_size,
                              hipStream_t stream) {
    const float* input = (const float*)d_in[0];
    const float* w_ih1 = (const float*)d_in[1];
    const float* w_hh1 = (const float*)d_in[2];
    const float* b_ih1 = (const float*)d_in[3];
    const float* b_hh1 = (const float*)d_in[4];
    const float* w_ih2 = (const float*)d_in[5];
    const float* w_hh2 = (const float*)d_in[6];
    const float* b_ih2 = (const float*)d_in[7];
    const float* b_hh2 = (const float*)d_in[8];
    const float* w_ih3 = (const float*)d_in[9];
    const float* w_hh3 = (const float*)d_in[10];
    const float* b_ih3 = (const float*)d_in[11];
    const float* b_hh3 = (const float*)d_in[12];
    const float* w_lin = (const float*)d_in[13];
    const float* b_lin = (const float*)d_in[14];
    float* out = (float*)d_out;

    const int B = in_sizes[0] / TT;          // 8192
    const int groups = B / 2;                // 2 elements per 16-lane group
    const int threads = 256;
    const int blocks = (groups * 16) / threads;  // 256

    lstm3_kernel<<<blocks, threads, 0, stream>>>(
        input, w_ih1, w_hh1, b_ih1, b_hh1,
        w_ih2, w_hh2, b_ih2, b_hh2,
        w_ih3, w_hh3, b_ih3, b_hh3,
        w_lin, b_lin, out, B);
}